// Round 4
// baseline (892.592 us; speedup 1.0000x reference)
//
#include <hip/hip_runtime.h>

// ---------------- problem constants ----------------
#define D_MODEL 1024
#define HID     2752
#define NEXP    8
#define NTOK    4096
#define ALPHA   0.05f

typedef __bf16 bf16_t;
typedef bf16_t bf16x8 __attribute__((ext_vector_type(8)));
typedef float  f32x4  __attribute__((ext_vector_type(4)));

__device__ inline unsigned short f2bf(float f) {
    unsigned int u = __float_as_uint(f);
    u += 0x7fffu + ((u >> 16) & 1u);   // round-to-nearest-even
    return (unsigned short)(u >> 16);
}

__device__ inline bf16x8 ldsFrag(const unsigned short* p) {
    union { uint4 u; bf16x8 b; } t;
    t.u = *(const uint4*)p;
    return t.b;
}

__device__ inline void gload_lds16(const void* g, void* l) {
    __builtin_amdgcn_global_load_lds((const __attribute__((address_space(1))) void*)g,
                                     (__attribute__((address_space(3))) void*)l, 16, 0, 0);
}

// ---------------- x -> bf16 ----------------
__global__ void tobf16_kernel(const float* __restrict__ x, unsigned short* __restrict__ xbf) {
    int i = (blockIdx.x * 256 + threadIdx.x) * 8;
    float4 a = *(const float4*)(x + i);
    float4 b = *(const float4*)(x + i + 4);
    uint4 o;
    o.x = (unsigned)f2bf(a.x) | ((unsigned)f2bf(a.y) << 16);
    o.y = (unsigned)f2bf(a.z) | ((unsigned)f2bf(a.w) << 16);
    o.z = (unsigned)f2bf(b.x) | ((unsigned)f2bf(b.y) << 16);
    o.w = (unsigned)f2bf(b.z) | ((unsigned)f2bf(b.w) << 16);
    *(uint4*)(xbf + i) = o;
}

// ---------------- weight transpose+convert: [R][C] f32 -> [C][R] bf16 ----------------
__global__ __launch_bounds__(256) void transposeUV_kernel(const float* __restrict__ Wu,
                                                          const float* __restrict__ Wv,
                                                          unsigned short* __restrict__ WuT,
                                                          unsigned short* __restrict__ WvT) {
    __shared__ float tile[64 * 65];
    const int z = blockIdx.z;
    const int e = z & 7;
    const float* src = ((z < 8) ? Wu : Wv) + (size_t)e * D_MODEL * HID;
    unsigned short* dst = ((z < 8) ? WuT : WvT) + (size_t)e * D_MODEL * HID;
    const int c0 = blockIdx.x * 64, r0 = blockIdx.y * 64;
    const int tid = threadIdx.x;
#pragma unroll
    for (int j = 0; j < 4; ++j) {
        int f = j * 256 + tid;
        int row = f >> 4, c4 = f & 15;
        float4 v = *(const float4*)(src + (size_t)(r0 + row) * HID + c0 + c4 * 4);
        float* t = &tile[row * 65 + c4 * 4];
        t[0] = v.x; t[1] = v.y; t[2] = v.z; t[3] = v.w;
    }
    __syncthreads();
#pragma unroll
    for (int j = 0; j < 2; ++j) {
        int f = j * 256 + tid;
        int orow = f >> 3, kc = f & 7;
        unsigned short pk[8];
#pragma unroll
        for (int q = 0; q < 8; ++q) pk[q] = f2bf(tile[(kc * 8 + q) * 65 + orow]);
        *(uint4*)(dst + (size_t)(c0 + orow) * D_MODEL + r0 + kc * 8) = *(uint4*)pk;
    }
}

__global__ __launch_bounds__(256) void transpose_kernel(const float* __restrict__ in,
                                                        unsigned short* __restrict__ out,
                                                        int R, int C) {
    __shared__ float tile[64 * 65];
    const int e = blockIdx.z;
    const float* src = in + (size_t)e * R * C;
    unsigned short* dst = out + (size_t)e * R * C;
    const int c0 = blockIdx.x * 64, r0 = blockIdx.y * 64;
    const int tid = threadIdx.x;
#pragma unroll
    for (int j = 0; j < 4; ++j) {
        int f = j * 256 + tid;
        int row = f >> 4, c4 = f & 15;
        float4 v = *(const float4*)(src + (size_t)(r0 + row) * C + c0 + c4 * 4);
        float* t = &tile[row * 65 + c4 * 4];
        t[0] = v.x; t[1] = v.y; t[2] = v.z; t[3] = v.w;
    }
    __syncthreads();
#pragma unroll
    for (int j = 0; j < 2; ++j) {
        int f = j * 256 + tid;
        int orow = f >> 3, kc = f & 7;
        unsigned short pk[8];
#pragma unroll
        for (int q = 0; q < 8; ++q) pk[q] = f2bf(tile[(kc * 8 + q) * 65 + orow]);
        *(uint4*)(dst + (size_t)(c0 + orow) * R + r0 + kc * 8) = *(uint4*)pk;
    }
}

// ---------------- router ----------------
__global__ void router_kernel(const float* __restrict__ x, const float* __restrict__ Wg,
                              const float* __restrict__ bg,
                              int* __restrict__ eidx, float* __restrict__ gate_p,
                              int* __restrict__ counts, float* __restrict__ ce_sum) {
    __shared__ float ceS[8];
    __shared__ int   cntS[8];
    int tid = threadIdx.x;
    if (tid < 8) { ceS[tid] = 0.f; cntS[tid] = 0; }
    __syncthreads();

    int wid = tid >> 6, lane = tid & 63;
    int t = blockIdx.x * 16 + wid;
    const float* xr = x + (size_t)t * D_MODEL;

    float acc[8];
#pragma unroll
    for (int e = 0; e < 8; ++e) acc[e] = 0.f;

#pragma unroll
    for (int c = 0; c < 4; ++c) {
        int i0 = c * 256 + lane * 4;
        float4 xv = *(const float4*)(xr + i0);
#pragma unroll
        for (int j = 0; j < 4; ++j) {
            const float* wr = Wg + (size_t)(i0 + j) * 8;
            float4 lo = *(const float4*)(wr);
            float4 hi = *(const float4*)(wr + 4);
            float xs = (&xv.x)[j];
            acc[0] += xs * lo.x; acc[1] += xs * lo.y;
            acc[2] += xs * lo.z; acc[3] += xs * lo.w;
            acc[4] += xs * hi.x; acc[5] += xs * hi.y;
            acc[6] += xs * hi.z; acc[7] += xs * hi.w;
        }
    }
#pragma unroll
    for (int e = 0; e < 8; ++e) {
#pragma unroll
        for (int off = 32; off > 0; off >>= 1)
            acc[e] += __shfl_xor(acc[e], off, 64);
    }

    if (lane == 0) {
        float lg[8];
#pragma unroll
        for (int e = 0; e < 8; ++e) lg[e] = acc[e] + bg[e];
        float mx = lg[0]; int am = 0;
#pragma unroll
        for (int e = 1; e < 8; ++e) { if (lg[e] > mx) { mx = lg[e]; am = e; } }
        float ex[8], s = 0.f;
#pragma unroll
        for (int e = 0; e < 8; ++e) { ex[e] = __expf(lg[e] - mx); s += ex[e]; }
        float inv = 1.f / s;
#pragma unroll
        for (int e = 0; e < 8; ++e) atomicAdd(&ceS[e], ex[e] * inv);
        atomicAdd(&cntS[am], 1);
        eidx[t] = am;
        gate_p[t] = ex[am] * inv;
    }
    __syncthreads();
    if (tid < 8) atomicAdd(&ce_sum[tid], ceS[tid]);
    if (tid >= 8 && tid < 16) atomicAdd(&counts[tid - 8], cntS[tid - 8]);
}

// ---------------- offsets + aux loss ----------------
__global__ void offsets_aux_kernel(const int* __restrict__ counts, const float* __restrict__ ce_sum,
                                   int* __restrict__ offs, float* __restrict__ aux_out) {
    if (threadIdx.x == 0) {
        int off = 0; float aux = 0.f;
        for (int e = 0; e < 8; ++e) {
            offs[e] = off; off += counts[e];
            aux += ((float)counts[e] / (float)NTOK) * (ce_sum[e] / (float)NTOK);
        }
        aux_out[0] = ALPHA * (float)NEXP * aux;
    }
}

// ---------------- scatter ----------------
__global__ void scatter_kernel(const int* __restrict__ eidx, const int* __restrict__ offs,
                               int* __restrict__ fill, int* __restrict__ toks) {
    int t = blockIdx.x * 256 + threadIdx.x;
    int e = eidx[t];
    int pos = atomicAdd(&fill[e], 1);
    toks[offs[e] + pos] = t;
}

// ---------------- GEMM1: h = silu(X WuT^T) * (X WvT^T), bf16 out ----------------
// 128m x 64n tile, BK=64, 4 waves (each 64x32), double-buffered 2-phase.
// LDS 64KB -> 2 blocks/CU. HID = 43*64 exactly -> no column guards.
__global__ __launch_bounds__(256, 2) void gemm1_kernel(
    const unsigned short* __restrict__ WuT, const unsigned short* __restrict__ WvT,
    const unsigned short* __restrict__ xbf,
    const int* __restrict__ toks, const int* __restrict__ counts, const int* __restrict__ offs,
    unsigned short* __restrict__ hbuf) {
    const int e = blockIdx.z;
    const int Ne = counts[e];
    const int mt = blockIdx.x;
    if (mt * 128 >= Ne) return;
    const int nt = blockIdx.y;
    const int slot0 = offs[e] + mt * 128;
    const int rowsV = min(128, Ne - mt * 128);
    const int ncol0 = nt * 64;

    __shared__ unsigned short As[2][128 * 64];
    __shared__ unsigned short Bus[2][64 * 64];
    __shared__ unsigned short Bvs[2][64 * 64];

    const int tid = threadIdx.x;

    // A: 4 chunks/thread (1024 total), B: 2 chunks/thread each (512 total)
    const unsigned short* aS[4];
    int aOff[4];
#pragma unroll
    for (int i = 0; i < 4; ++i) {
        int c = i * 256 + tid;
        int r = c >> 3, ch = c & 7;
        int srcOff = (ch ^ (r & 7)) * 8;
        int ar = min(r, rowsV - 1);
        int tok = toks[slot0 + ar];
        aS[i] = xbf + (size_t)tok * D_MODEL + srcOff;
        aOff[i] = c * 8;
    }
    const unsigned short *buS[2], *bvS[2];
    int bOff[2];
#pragma unroll
    for (int i = 0; i < 2; ++i) {
        int c = i * 256 + tid;
        int r = c >> 3, ch = c & 7;
        int srcOff = (ch ^ (r & 7)) * 8;
        int bn = ncol0 + r;
        buS[i] = WuT + ((size_t)e * HID + bn) * D_MODEL + srcOff;
        bvS[i] = WvT + ((size_t)e * HID + bn) * D_MODEL + srcOff;
        bOff[i] = c * 8;
    }

    f32x4 accU[4][2], accV[4][2];
#pragma unroll
    for (int m = 0; m < 4; ++m)
#pragma unroll
        for (int n = 0; n < 2; ++n) {
            accU[m][n] = (f32x4){0.f, 0.f, 0.f, 0.f};
            accV[m][n] = (f32x4){0.f, 0.f, 0.f, 0.f};
        }

    const int lane = tid & 63;
    const int w = tid >> 6;
    const int rbase = (w >> 1) * 64;
    const int cbase = (w & 1) * 32;
    const int lrow = lane & 15;
    const int lchunk = lane >> 4;

    // prologue: stage K-step 0 into buffer 0
#pragma unroll
    for (int i = 0; i < 4; ++i) { gload_lds16(aS[i], &As[0][aOff[i]]); aS[i] += 64; }
#pragma unroll
    for (int i = 0; i < 2; ++i) {
        gload_lds16(buS[i], &Bus[0][bOff[i]]);
        gload_lds16(bvS[i], &Bvs[0][bOff[i]]);
        buS[i] += 64; bvS[i] += 64;
    }
    __syncthreads();

    int cur = 0;
    for (int ks = 0; ks < 16; ++ks) {
        if (ks < 15) {
#pragma unroll
            for (int i = 0; i < 4; ++i) { gload_lds16(aS[i], &As[cur ^ 1][aOff[i]]); aS[i] += 64; }
#pragma unroll
            for (int i = 0; i < 2; ++i) {
                gload_lds16(buS[i], &Bus[cur ^ 1][bOff[i]]);
                gload_lds16(bvS[i], &Bvs[cur ^ 1][bOff[i]]);
                buS[i] += 64; bvS[i] += 64;
            }
        }
#pragma unroll
        for (int kk = 0; kk < 2; ++kk) {
            const int g = kk * 4 + lchunk;
            bf16x8 af[4], bu[2], bv[2];
#pragma unroll
            for (int m = 0; m < 4; ++m) {
                int r = rbase + m * 16 + lrow;
                af[m] = ldsFrag(&As[cur][r * 64 + ((g ^ (r & 7)) * 8)]);
            }
#pragma unroll
            for (int n = 0; n < 2; ++n) {
                int rn = cbase + n * 16 + lrow;
                int off = rn * 64 + ((g ^ (rn & 7)) * 8);
                bu[n] = ldsFrag(&Bus[cur][off]);
                bv[n] = ldsFrag(&Bvs[cur][off]);
            }
#pragma unroll
            for (int m = 0; m < 4; ++m)
#pragma unroll
                for (int n = 0; n < 2; ++n) {
                    accU[m][n] = __builtin_amdgcn_mfma_f32_16x16x32_bf16(af[m], bu[n], accU[m][n], 0, 0, 0);
                    accV[m][n] = __builtin_amdgcn_mfma_f32_16x16x32_bf16(af[m], bv[n], accV[m][n], 0, 0, 0);
                }
        }
        __syncthreads();   // drains next-step loads + LDS handoff
        cur ^= 1;
    }

    // epilogue: h = silu(u) * v (bf16)
#pragma unroll
    for (int m = 0; m < 4; ++m) {
#pragma unroll
        for (int i = 0; i < 4; ++i) {
            int r = rbase + m * 16 + (lane >> 4) * 4 + i;
            if (r >= rowsV) continue;
            size_t rowOff = (size_t)(slot0 + r) * HID + ncol0;
#pragma unroll
            for (int n = 0; n < 2; ++n) {
                int c = cbase + n * 16 + (lane & 15);
                float u = accU[m][n][i];
                float v = accV[m][n][i];
                float s = u / (1.f + __expf(-u));
                hbuf[rowOff + c] = f2bf(s * v);
            }
        }
    }
}

// ---------------- GEMM2: y[tok] = p * (h WdT^T), 128m x 64n, double-buffered ----------------
__global__ __launch_bounds__(256, 2) void gemm2_kernel(
    const unsigned short* __restrict__ WdT, const unsigned short* __restrict__ hbuf,
    const int* __restrict__ toks, const int* __restrict__ counts, const int* __restrict__ offs,
    const float* __restrict__ gate_p, float* __restrict__ yout) {
    const int e = blockIdx.z;
    const int Ne = counts[e];
    const int mt = blockIdx.x;
    if (mt * 128 >= Ne) return;
    const int nt = blockIdx.y;
    const int slot0 = offs[e] + mt * 128;
    const int rowsV = min(128, Ne - mt * 128);
    const int ncol0 = nt * 64;

    __shared__ unsigned short As[2][128 * 64];
    __shared__ unsigned short Bs[2][64 * 64];

    const int tid = threadIdx.x;

    const unsigned short* aS[4];
    int aOff[4];
#pragma unroll
    for (int i = 0; i < 4; ++i) {
        int c = i * 256 + tid;
        int r = c >> 3, ch = c & 7;
        int srcOff = (ch ^ (r & 7)) * 8;
        int ar = min(r, rowsV - 1);
        aS[i] = hbuf + (size_t)(slot0 + ar) * HID + srcOff;
        aOff[i] = c * 8;
    }
    const unsigned short* bS[2];
    int bOff[2];
#pragma unroll
    for (int i = 0; i < 2; ++i) {
        int c = i * 256 + tid;
        int r = c >> 3, ch = c & 7;
        int srcOff = (ch ^ (r & 7)) * 8;
        bS[i] = WdT + ((size_t)e * D_MODEL + ncol0 + r) * HID + srcOff;
        bOff[i] = c * 8;
    }

    f32x4 acc[4][2];
#pragma unroll
    for (int m = 0; m < 4; ++m)
#pragma unroll
        for (int n = 0; n < 2; ++n) acc[m][n] = (f32x4){0.f, 0.f, 0.f, 0.f};

    const int lane = tid & 63;
    const int w = tid >> 6;
    const int rbase = (w >> 1) * 64;
    const int cbase = (w & 1) * 32;
    const int lrow = lane & 15;
    const int lchunk = lane >> 4;

    // prologue
#pragma unroll
    for (int i = 0; i < 4; ++i) { gload_lds16(aS[i], &As[0][aOff[i]]); aS[i] += 64; }
#pragma unroll
    for (int i = 0; i < 2; ++i) { gload_lds16(bS[i], &Bs[0][bOff[i]]); bS[i] += 64; }
    __syncthreads();

    int cur = 0;
    for (int ks = 0; ks < 43; ++ks) {
        if (ks < 42) {
#pragma unroll
            for (int i = 0; i < 4; ++i) { gload_lds16(aS[i], &As[cur ^ 1][aOff[i]]); aS[i] += 64; }
#pragma unroll
            for (int i = 0; i < 2; ++i) { gload_lds16(bS[i], &Bs[cur ^ 1][bOff[i]]); bS[i] += 64; }
        }
#pragma unroll
        for (int kk = 0; kk < 2; ++kk) {
            const int g = kk * 4 + lchunk;
            bf16x8 af[4], bf[2];
#pragma unroll
            for (int m = 0; m < 4; ++m) {
                int r = rbase + m * 16 + lrow;
                af[m] = ldsFrag(&As[cur][r * 64 + ((g ^ (r & 7)) * 8)]);
            }
#pragma unroll
            for (int n = 0; n < 2; ++n) {
                int rn = cbase + n * 16 + lrow;
                bf[n] = ldsFrag(&Bs[cur][rn * 64 + ((g ^ (rn & 7)) * 8)]);
            }
#pragma unroll
            for (int m = 0; m < 4; ++m)
#pragma unroll
                for (int n = 0; n < 2; ++n)
                    acc[m][n] = __builtin_amdgcn_mfma_f32_16x16x32_bf16(af[m], bf[n], acc[m][n], 0, 0, 0);
        }
        __syncthreads();
        cur ^= 1;
    }

#pragma unroll
    for (int m = 0; m < 4; ++m) {
#pragma unroll
        for (int i = 0; i < 4; ++i) {
            int r = rbase + m * 16 + (lane >> 4) * 4 + i;
            if (r >= rowsV) continue;
            int tok = toks[slot0 + r];
            float p = gate_p[tok];
            float* yrow = yout + (size_t)tok * D_MODEL + ncol0;
#pragma unroll
            for (int n = 0; n < 2; ++n) {
                int c = cbase + n * 16 + (lane & 15);
                yrow[c] = p * acc[m][n][i];
            }
        }
    }
}

// ---------------- launch ----------------
extern "C" void kernel_launch(void* const* d_in, const int* in_sizes, int n_in,
                              void* d_out, int out_size, void* d_ws, size_t ws_size,
                              hipStream_t stream) {
    const float* x  = (const float*)d_in[0];
    const float* Wg = (const float*)d_in[1];
    const float* bg = (const float*)d_in[2];
    const float* Wu = (const float*)d_in[3];
    const float* Wv = (const float*)d_in[4];
    const float* Wd = (const float*)d_in[5];
    float* yout = (float*)d_out;
    float* aux_out = yout + (size_t)NTOK * D_MODEL;

    char* ws = (char*)d_ws;
    int*   counts = (int*)(ws + 0);
    int*   offs   = (int*)(ws + 32);
    float* ce_sum = (float*)(ws + 64);
    int*   fill   = (int*)(ws + 96);
    int*   eidx   = (int*)(ws + 128);
    float* gate_p = (float*)(ws + 16512);
    int*   toks   = (int*)(ws + 32896);
    unsigned short* xbf  = (unsigned short*)(ws + 65536);      // 8 MB
    unsigned short* hbuf = (unsigned short*)(ws + 8454144);    // 22.5 MB
    unsigned short* WuT  = (unsigned short*)(ws + 30998528);   // 45 MB
    unsigned short* WvT  = (unsigned short*)(ws + 76087296);   // 45 MB
    unsigned short* WdT  = WuT;                                // reused after gemm1

    hipMemsetAsync(ws, 0, 128, stream);
    tobf16_kernel<<<2048, 256, 0, stream>>>(x, xbf);
    router_kernel<<<256, 1024, 0, stream>>>(x, Wg, bg, eidx, gate_p, counts, ce_sum);
    offsets_aux_kernel<<<1, 64, 0, stream>>>(counts, ce_sum, offs, aux_out);
    scatter_kernel<<<16, 256, 0, stream>>>(eidx, offs, fill, toks);
    transposeUV_kernel<<<dim3(HID / 64, D_MODEL / 64, 16), 256, 0, stream>>>(Wu, Wv, WuT, WvT);
    gemm1_kernel<<<dim3(32, 43, 8), 256, 0, stream>>>(WuT, WvT, xbf, toks, counts, offs, hbuf);
    transpose_kernel<<<dim3(D_MODEL / 64, HID / 64, 8), 256, 0, stream>>>(Wd, WdT, HID, D_MODEL);
    gemm2_kernel<<<dim3(32, 16, 8), 256, 0, stream>>>(WdT, hbuf, toks, counts, offs, gate_p, yout);
}

// Round 5
// 279.515 us; speedup vs baseline: 3.1934x; 3.1934x over previous
//
#include <hip/hip_runtime.h>

// ---------------- problem constants ----------------
#define D_MODEL 1024
#define HID     2752
#define NEXP    8
#define NTOK    4096
#define ALPHA   0.05f

typedef __bf16 bf16_t;
typedef bf16_t bf16x8 __attribute__((ext_vector_type(8)));
typedef float  f32x4  __attribute__((ext_vector_type(4)));

__device__ inline unsigned short f2bf(float f) {
    unsigned int u = __float_as_uint(f);
    u += 0x7fffu + ((u >> 16) & 1u);   // round-to-nearest-even
    return (unsigned short)(u >> 16);
}

__device__ inline bf16x8 ldsFrag(const unsigned short* p) {
    union { uint4 u; bf16x8 b; } t;
    t.u = *(const uint4*)p;
    return t.b;
}

__device__ inline void gload_lds16(const void* g, void* l) {
    __builtin_amdgcn_global_load_lds((const __attribute__((address_space(1))) void*)g,
                                     (__attribute__((address_space(3))) void*)l, 16, 0, 0);
}

// ---------------- x -> bf16 ----------------
__global__ void tobf16_kernel(const float* __restrict__ x, unsigned short* __restrict__ xbf) {
    int i = (blockIdx.x * 256 + threadIdx.x) * 8;
    float4 a = *(const float4*)(x + i);
    float4 b = *(const float4*)(x + i + 4);
    uint4 o;
    o.x = (unsigned)f2bf(a.x) | ((unsigned)f2bf(a.y) << 16);
    o.y = (unsigned)f2bf(a.z) | ((unsigned)f2bf(a.w) << 16);
    o.z = (unsigned)f2bf(b.x) | ((unsigned)f2bf(b.y) << 16);
    o.w = (unsigned)f2bf(b.z) | ((unsigned)f2bf(b.w) << 16);
    *(uint4*)(xbf + i) = o;
}

// ---------------- weight transpose+convert: [R][C] f32 -> [C][R] bf16 ----------------
__global__ __launch_bounds__(256) void transposeUV_kernel(const float* __restrict__ Wu,
                                                          const float* __restrict__ Wv,
                                                          unsigned short* __restrict__ WuT,
                                                          unsigned short* __restrict__ WvT) {
    __shared__ float tile[64 * 65];
    const int z = blockIdx.z;
    const int e = z & 7;
    const float* src = ((z < 8) ? Wu : Wv) + (size_t)e * D_MODEL * HID;
    unsigned short* dst = ((z < 8) ? WuT : WvT) + (size_t)e * D_MODEL * HID;
    const int c0 = blockIdx.x * 64, r0 = blockIdx.y * 64;
    const int tid = threadIdx.x;
#pragma unroll
    for (int j = 0; j < 4; ++j) {
        int f = j * 256 + tid;
        int row = f >> 4, c4 = f & 15;
        float4 v = *(const float4*)(src + (size_t)(r0 + row) * HID + c0 + c4 * 4);
        float* t = &tile[row * 65 + c4 * 4];
        t[0] = v.x; t[1] = v.y; t[2] = v.z; t[3] = v.w;
    }
    __syncthreads();
#pragma unroll
    for (int j = 0; j < 2; ++j) {
        int f = j * 256 + tid;
        int orow = f >> 3, kc = f & 7;
        unsigned short pk[8];
#pragma unroll
        for (int q = 0; q < 8; ++q) pk[q] = f2bf(tile[(kc * 8 + q) * 65 + orow]);
        *(uint4*)(dst + (size_t)(c0 + orow) * D_MODEL + r0 + kc * 8) = *(uint4*)pk;
    }
}

__global__ __launch_bounds__(256) void transpose_kernel(const float* __restrict__ in,
                                                        unsigned short* __restrict__ out,
                                                        int R, int C) {
    __shared__ float tile[64 * 65];
    const int e = blockIdx.z;
    const float* src = in + (size_t)e * R * C;
    unsigned short* dst = out + (size_t)e * R * C;
    const int c0 = blockIdx.x * 64, r0 = blockIdx.y * 64;
    const int tid = threadIdx.x;
#pragma unroll
    for (int j = 0; j < 4; ++j) {
        int f = j * 256 + tid;
        int row = f >> 4, c4 = f & 15;
        float4 v = *(const float4*)(src + (size_t)(r0 + row) * C + c0 + c4 * 4);
        float* t = &tile[row * 65 + c4 * 4];
        t[0] = v.x; t[1] = v.y; t[2] = v.z; t[3] = v.w;
    }
    __syncthreads();
#pragma unroll
    for (int j = 0; j < 2; ++j) {
        int f = j * 256 + tid;
        int orow = f >> 3, kc = f & 7;
        unsigned short pk[8];
#pragma unroll
        for (int q = 0; q < 8; ++q) pk[q] = f2bf(tile[(kc * 8 + q) * 65 + orow]);
        *(uint4*)(dst + (size_t)(c0 + orow) * R + r0 + kc * 8) = *(uint4*)pk;
    }
}

// ---------------- router ----------------
__global__ void router_kernel(const float* __restrict__ x, const float* __restrict__ Wg,
                              const float* __restrict__ bg,
                              int* __restrict__ eidx, float* __restrict__ gate_p,
                              int* __restrict__ counts, float* __restrict__ ce_sum) {
    __shared__ float ceS[8];
    __shared__ int   cntS[8];
    int tid = threadIdx.x;
    if (tid < 8) { ceS[tid] = 0.f; cntS[tid] = 0; }
    __syncthreads();

    int wid = tid >> 6, lane = tid & 63;
    int t = blockIdx.x * 16 + wid;
    const float* xr = x + (size_t)t * D_MODEL;

    float acc[8];
#pragma unroll
    for (int e = 0; e < 8; ++e) acc[e] = 0.f;

#pragma unroll
    for (int c = 0; c < 4; ++c) {
        int i0 = c * 256 + lane * 4;
        float4 xv = *(const float4*)(xr + i0);
#pragma unroll
        for (int j = 0; j < 4; ++j) {
            const float* wr = Wg + (size_t)(i0 + j) * 8;
            float4 lo = *(const float4*)(wr);
            float4 hi = *(const float4*)(wr + 4);
            float xs = (&xv.x)[j];
            acc[0] += xs * lo.x; acc[1] += xs * lo.y;
            acc[2] += xs * lo.z; acc[3] += xs * lo.w;
            acc[4] += xs * hi.x; acc[5] += xs * hi.y;
            acc[6] += xs * hi.z; acc[7] += xs * hi.w;
        }
    }
#pragma unroll
    for (int e = 0; e < 8; ++e) {
#pragma unroll
        for (int off = 32; off > 0; off >>= 1)
            acc[e] += __shfl_xor(acc[e], off, 64);
    }

    if (lane == 0) {
        float lg[8];
#pragma unroll
        for (int e = 0; e < 8; ++e) lg[e] = acc[e] + bg[e];
        float mx = lg[0]; int am = 0;
#pragma unroll
        for (int e = 1; e < 8; ++e) { if (lg[e] > mx) { mx = lg[e]; am = e; } }
        float ex[8], s = 0.f;
#pragma unroll
        for (int e = 0; e < 8; ++e) { ex[e] = __expf(lg[e] - mx); s += ex[e]; }
        float inv = 1.f / s;
#pragma unroll
        for (int e = 0; e < 8; ++e) atomicAdd(&ceS[e], ex[e] * inv);
        atomicAdd(&cntS[am], 1);
        eidx[t] = am;
        gate_p[t] = ex[am] * inv;
    }
    __syncthreads();
    if (tid < 8) atomicAdd(&ce_sum[tid], ceS[tid]);
    if (tid >= 8 && tid < 16) atomicAdd(&counts[tid - 8], cntS[tid - 8]);
}

// ---------------- offsets + aux loss ----------------
__global__ void offsets_aux_kernel(const int* __restrict__ counts, const float* __restrict__ ce_sum,
                                   int* __restrict__ offs, float* __restrict__ aux_out) {
    if (threadIdx.x == 0) {
        int off = 0; float aux = 0.f;
        for (int e = 0; e < 8; ++e) {
            offs[e] = off; off += counts[e];
            aux += ((float)counts[e] / (float)NTOK) * (ce_sum[e] / (float)NTOK);
        }
        aux_out[0] = ALPHA * (float)NEXP * aux;
    }
}

// ---------------- scatter ----------------
__global__ void scatter_kernel(const int* __restrict__ eidx, const int* __restrict__ offs,
                               int* __restrict__ fill, int* __restrict__ toks) {
    int t = blockIdx.x * 256 + threadIdx.x;
    int e = eidx[t];
    int pos = atomicAdd(&fill[e], 1);
    toks[offs[e] + pos] = t;
}

// ---------------- GEMM1: h = silu(X WuT^T) * (X WvT^T), bf16 out ----------------
// 128x128 tile, BK=64, 4 waves, single-buffer 2-barrier (round-2 proven: 101us).
__global__ __launch_bounds__(256, 2) void gemm1_kernel(
    const unsigned short* __restrict__ WuT, const unsigned short* __restrict__ WvT,
    const unsigned short* __restrict__ xbf,
    const int* __restrict__ toks, const int* __restrict__ counts, const int* __restrict__ offs,
    unsigned short* __restrict__ hbuf) {
    const int e = blockIdx.z;
    const int Ne = counts[e];
    const int mt = blockIdx.y;
    if (mt * 128 >= Ne) return;
    const int nt = blockIdx.x;
    const int slot0 = offs[e] + mt * 128;
    const int rowsV = min(128, Ne - mt * 128);
    const int ncol0 = nt * 128;
    const int colsV = min(128, HID - ncol0);

    __shared__ unsigned short As[128 * 64];
    __shared__ unsigned short Bus[128 * 64];
    __shared__ unsigned short Bvs[128 * 64];

    const int tid = threadIdx.x;

    const unsigned short* aS[4];
    const unsigned short* buS[4];
    const unsigned short* bvS[4];
    unsigned short* aD[4];
    unsigned short* buD[4];
    unsigned short* bvD[4];
#pragma unroll
    for (int i = 0; i < 4; ++i) {
        int c = i * 256 + tid;
        int r = c >> 3, ch = c & 7;
        int srcOff = ((ch ^ (r & 7)) * 8);
        int ar = min(r, rowsV - 1);
        int tok = toks[slot0 + ar];
        aS[i] = xbf + (size_t)tok * D_MODEL + srcOff;
        int bn = ncol0 + min(r, colsV - 1);
        buS[i] = WuT + ((size_t)e * HID + bn) * D_MODEL + srcOff;
        bvS[i] = WvT + ((size_t)e * HID + bn) * D_MODEL + srcOff;
        aD[i]  = As  + c * 8;
        buD[i] = Bus + c * 8;
        bvD[i] = Bvs + c * 8;
    }

    f32x4 accU[4][4], accV[4][4];
#pragma unroll
    for (int m = 0; m < 4; ++m)
#pragma unroll
        for (int n = 0; n < 4; ++n) {
            accU[m][n] = (f32x4){0.f, 0.f, 0.f, 0.f};
            accV[m][n] = (f32x4){0.f, 0.f, 0.f, 0.f};
        }

    const int lane = tid & 63;
    const int w = tid >> 6;
    const int rbase = (w >> 1) * 64;
    const int cbase = (w & 1) * 64;
    const int lrow = lane & 15;
    const int lchunk = lane >> 4;

    for (int ks = 0; ks < 16; ++ks) {
#pragma unroll
        for (int i = 0; i < 4; ++i) gload_lds16(aS[i],  aD[i]);
#pragma unroll
        for (int i = 0; i < 4; ++i) gload_lds16(buS[i], buD[i]);
#pragma unroll
        for (int i = 0; i < 4; ++i) gload_lds16(bvS[i], bvD[i]);
#pragma unroll
        for (int i = 0; i < 4; ++i) { aS[i] += 64; buS[i] += 64; bvS[i] += 64; }
        __syncthreads();

#pragma unroll
        for (int kk = 0; kk < 2; ++kk) {
            const int g = kk * 4 + lchunk;
            bf16x8 af[4], bu[4], bv[4];
#pragma unroll
            for (int m = 0; m < 4; ++m) {
                int r = rbase + m * 16 + lrow;
                af[m] = ldsFrag(&As[r * 64 + ((g ^ (r & 7)) * 8)]);
            }
#pragma unroll
            for (int n = 0; n < 4; ++n) {
                int rn = cbase + n * 16 + lrow;
                int off = rn * 64 + ((g ^ (rn & 7)) * 8);
                bu[n] = ldsFrag(&Bus[off]);
                bv[n] = ldsFrag(&Bvs[off]);
            }
#pragma unroll
            for (int m = 0; m < 4; ++m)
#pragma unroll
                for (int n = 0; n < 4; ++n) {
                    accU[m][n] = __builtin_amdgcn_mfma_f32_16x16x32_bf16(af[m], bu[n], accU[m][n], 0, 0, 0);
                    accV[m][n] = __builtin_amdgcn_mfma_f32_16x16x32_bf16(af[m], bv[n], accV[m][n], 0, 0, 0);
                }
        }
        __syncthreads();
    }

    // epilogue: h = silu(u) * v (bf16)
#pragma unroll
    for (int m = 0; m < 4; ++m) {
#pragma unroll
        for (int i = 0; i < 4; ++i) {
            int r = rbase + m * 16 + (lane >> 4) * 4 + i;
            if (r >= rowsV) continue;
            size_t rowOff = (size_t)(slot0 + r) * HID + ncol0;
#pragma unroll
            for (int n = 0; n < 4; ++n) {
                int c = cbase + n * 16 + (lane & 15);
                if (c < colsV) {
                    float u = accU[m][n][i];
                    float v = accV[m][n][i];
                    float s = u / (1.f + __expf(-u));
                    hbuf[rowOff + c] = f2bf(s * v);
                }
            }
        }
    }
}

// ---------------- GEMM2: y[tok] = p * (h WdT^T), 128m x 64n, single-buffer ----------------
// Same proven 2-barrier structure; BN=64 doubles active blocks (544 vs 288) and
// cuts LDS to 24KB (static 6 blocks/CU) for latency hiding via TLP.
__global__ __launch_bounds__(256, 2) void gemm2_kernel(
    const unsigned short* __restrict__ WdT, const unsigned short* __restrict__ hbuf,
    const int* __restrict__ toks, const int* __restrict__ counts, const int* __restrict__ offs,
    const float* __restrict__ gate_p, float* __restrict__ yout) {
    const int e = blockIdx.z;
    const int Ne = counts[e];
    const int mt = blockIdx.y;
    if (mt * 128 >= Ne) return;
    const int nt = blockIdx.x;
    const int slot0 = offs[e] + mt * 128;
    const int rowsV = min(128, Ne - mt * 128);
    const int ncol0 = nt * 64;

    __shared__ unsigned short As[128 * 64];
    __shared__ unsigned short Bs[64 * 64];

    const int tid = threadIdx.x;

    const unsigned short* aS[4];
    unsigned short* aD[4];
#pragma unroll
    for (int i = 0; i < 4; ++i) {
        int c = i * 256 + tid;
        int r = c >> 3, ch = c & 7;
        int srcOff = ((ch ^ (r & 7)) * 8);
        int ar = min(r, rowsV - 1);
        aS[i] = hbuf + (size_t)(slot0 + ar) * HID + srcOff;
        aD[i] = As + c * 8;
    }
    const unsigned short* bS[2];
    unsigned short* bD[2];
#pragma unroll
    for (int i = 0; i < 2; ++i) {
        int c = i * 256 + tid;
        int r = c >> 3, ch = c & 7;
        int srcOff = ((ch ^ (r & 7)) * 8);
        bS[i] = WdT + ((size_t)e * D_MODEL + ncol0 + r) * HID + srcOff;
        bD[i] = Bs + c * 8;
    }

    f32x4 acc[4][2];
#pragma unroll
    for (int m = 0; m < 4; ++m)
#pragma unroll
        for (int n = 0; n < 2; ++n) acc[m][n] = (f32x4){0.f, 0.f, 0.f, 0.f};

    const int lane = tid & 63;
    const int w = tid >> 6;
    const int rbase = (w >> 1) * 64;
    const int cbase = (w & 1) * 32;
    const int lrow = lane & 15;
    const int lchunk = lane >> 4;

    for (int ks = 0; ks < 43; ++ks) {
#pragma unroll
        for (int i = 0; i < 4; ++i) gload_lds16(aS[i], aD[i]);
#pragma unroll
        for (int i = 0; i < 2; ++i) gload_lds16(bS[i], bD[i]);
#pragma unroll
        for (int i = 0; i < 4; ++i) aS[i] += 64;
#pragma unroll
        for (int i = 0; i < 2; ++i) bS[i] += 64;
        __syncthreads();

#pragma unroll
        for (int kk = 0; kk < 2; ++kk) {
            const int g = kk * 4 + lchunk;
            bf16x8 af[4], bf[2];
#pragma unroll
            for (int m = 0; m < 4; ++m) {
                int r = rbase + m * 16 + lrow;
                af[m] = ldsFrag(&As[r * 64 + ((g ^ (r & 7)) * 8)]);
            }
#pragma unroll
            for (int n = 0; n < 2; ++n) {
                int rn = cbase + n * 16 + lrow;
                bf[n] = ldsFrag(&Bs[rn * 64 + ((g ^ (rn & 7)) * 8)]);
            }
#pragma unroll
            for (int m = 0; m < 4; ++m)
#pragma unroll
                for (int n = 0; n < 2; ++n)
                    acc[m][n] = __builtin_amdgcn_mfma_f32_16x16x32_bf16(af[m], bf[n], acc[m][n], 0, 0, 0);
        }
        __syncthreads();
    }

#pragma unroll
    for (int m = 0; m < 4; ++m) {
#pragma unroll
        for (int i = 0; i < 4; ++i) {
            int r = rbase + m * 16 + (lane >> 4) * 4 + i;
            if (r >= rowsV) continue;
            int tok = toks[slot0 + r];
            float p = gate_p[tok];
            float* yrow = yout + (size_t)tok * D_MODEL + ncol0;
#pragma unroll
            for (int n = 0; n < 2; ++n) {
                int c = cbase + n * 16 + (lane & 15);
                yrow[c] = p * acc[m][n][i];
            }
        }
    }
}

// ---------------- launch ----------------
extern "C" void kernel_launch(void* const* d_in, const int* in_sizes, int n_in,
                              void* d_out, int out_size, void* d_ws, size_t ws_size,
                              hipStream_t stream) {
    const float* x  = (const float*)d_in[0];
    const float* Wg = (const float*)d_in[1];
    const float* bg = (const float*)d_in[2];
    const float* Wu = (const float*)d_in[3];
    const float* Wv = (const float*)d_in[4];
    const float* Wd = (const float*)d_in[5];
    float* yout = (float*)d_out;
    float* aux_out = yout + (size_t)NTOK * D_MODEL;

    char* ws = (char*)d_ws;
    int*   counts = (int*)(ws + 0);
    int*   offs   = (int*)(ws + 32);
    float* ce_sum = (float*)(ws + 64);
    int*   fill   = (int*)(ws + 96);
    int*   eidx   = (int*)(ws + 128);
    float* gate_p = (float*)(ws + 16512);
    int*   toks   = (int*)(ws + 32896);
    unsigned short* xbf  = (unsigned short*)(ws + 65536);      // 8 MB
    unsigned short* hbuf = (unsigned short*)(ws + 8454144);    // 22.5 MB
    unsigned short* WuT  = (unsigned short*)(ws + 30998528);   // 45 MB
    unsigned short* WvT  = (unsigned short*)(ws + 76087296);   // 45 MB
    unsigned short* WdT  = WuT;                                // reused after gemm1

    hipMemsetAsync(ws, 0, 128, stream);
    tobf16_kernel<<<2048, 256, 0, stream>>>(x, xbf);
    router_kernel<<<256, 1024, 0, stream>>>(x, Wg, bg, eidx, gate_p, counts, ce_sum);
    offsets_aux_kernel<<<1, 64, 0, stream>>>(counts, ce_sum, offs, aux_out);
    scatter_kernel<<<16, 256, 0, stream>>>(eidx, offs, fill, toks);
    transposeUV_kernel<<<dim3(HID / 64, D_MODEL / 64, 16), 256, 0, stream>>>(Wu, Wv, WuT, WvT);
    gemm1_kernel<<<dim3(22, 32, 8), 256, 0, stream>>>(WuT, WvT, xbf, toks, counts, offs, hbuf);
    transpose_kernel<<<dim3(D_MODEL / 64, HID / 64, 8), 256, 0, stream>>>(Wd, WdT, HID, D_MODEL);
    gemm2_kernel<<<dim3(16, 32, 8), 256, 0, stream>>>(WdT, hbuf, toks, counts, offs, gate_p, yout);
}

// Round 6
// 269.001 us; speedup vs baseline: 3.3182x; 1.0391x over previous
//
#include <hip/hip_runtime.h>

// ---------------- problem constants ----------------
#define D_MODEL 1024
#define HID     2752
#define NEXP    8
#define NTOK    4096
#define ALPHA   0.05f

typedef __bf16 bf16_t;
typedef bf16_t bf16x8 __attribute__((ext_vector_type(8)));
typedef float  f32x4  __attribute__((ext_vector_type(4)));

__device__ inline unsigned short f2bf(float f) {
    unsigned int u = __float_as_uint(f);
    u += 0x7fffu + ((u >> 16) & 1u);   // round-to-nearest-even
    return (unsigned short)(u >> 16);
}

__device__ inline bf16x8 ldsFrag(const unsigned short* p) {
    union { uint4 u; bf16x8 b; } t;
    t.u = *(const uint4*)p;
    return t.b;
}

__device__ inline void gload_lds16(const void* g, void* l) {
    __builtin_amdgcn_global_load_lds((const __attribute__((address_space(1))) void*)g,
                                     (__attribute__((address_space(3))) void*)l, 16, 0, 0);
}

// ---------------- x -> bf16 ----------------
__global__ void tobf16_kernel(const float* __restrict__ x, unsigned short* __restrict__ xbf) {
    int i = (blockIdx.x * 256 + threadIdx.x) * 8;
    float4 a = *(const float4*)(x + i);
    float4 b = *(const float4*)(x + i + 4);
    uint4 o;
    o.x = (unsigned)f2bf(a.x) | ((unsigned)f2bf(a.y) << 16);
    o.y = (unsigned)f2bf(a.z) | ((unsigned)f2bf(a.w) << 16);
    o.z = (unsigned)f2bf(b.x) | ((unsigned)f2bf(b.y) << 16);
    o.w = (unsigned)f2bf(b.z) | ((unsigned)f2bf(b.w) << 16);
    *(uint4*)(xbf + i) = o;
}

// ---------------- weight transpose+convert: [R][C] f32 -> [C][R] bf16 ----------------
__global__ __launch_bounds__(256) void transposeUV_kernel(const float* __restrict__ Wu,
                                                          const float* __restrict__ Wv,
                                                          unsigned short* __restrict__ WuT,
                                                          unsigned short* __restrict__ WvT) {
    __shared__ float tile[64 * 65];
    const int z = blockIdx.z;
    const int e = z & 7;
    const float* src = ((z < 8) ? Wu : Wv) + (size_t)e * D_MODEL * HID;
    unsigned short* dst = ((z < 8) ? WuT : WvT) + (size_t)e * D_MODEL * HID;
    const int c0 = blockIdx.x * 64, r0 = blockIdx.y * 64;
    const int tid = threadIdx.x;
#pragma unroll
    for (int j = 0; j < 4; ++j) {
        int f = j * 256 + tid;
        int row = f >> 4, c4 = f & 15;
        float4 v = *(const float4*)(src + (size_t)(r0 + row) * HID + c0 + c4 * 4);
        float* t = &tile[row * 65 + c4 * 4];
        t[0] = v.x; t[1] = v.y; t[2] = v.z; t[3] = v.w;
    }
    __syncthreads();
#pragma unroll
    for (int j = 0; j < 2; ++j) {
        int f = j * 256 + tid;
        int orow = f >> 3, kc = f & 7;
        unsigned short pk[8];
#pragma unroll
        for (int q = 0; q < 8; ++q) pk[q] = f2bf(tile[(kc * 8 + q) * 65 + orow]);
        *(uint4*)(dst + (size_t)(c0 + orow) * D_MODEL + r0 + kc * 8) = *(uint4*)pk;
    }
}

__global__ __launch_bounds__(256) void transpose_kernel(const float* __restrict__ in,
                                                        unsigned short* __restrict__ out,
                                                        int R, int C) {
    __shared__ float tile[64 * 65];
    const int e = blockIdx.z;
    const float* src = in + (size_t)e * R * C;
    unsigned short* dst = out + (size_t)e * R * C;
    const int c0 = blockIdx.x * 64, r0 = blockIdx.y * 64;
    const int tid = threadIdx.x;
#pragma unroll
    for (int j = 0; j < 4; ++j) {
        int f = j * 256 + tid;
        int row = f >> 4, c4 = f & 15;
        float4 v = *(const float4*)(src + (size_t)(r0 + row) * C + c0 + c4 * 4);
        float* t = &tile[row * 65 + c4 * 4];
        t[0] = v.x; t[1] = v.y; t[2] = v.z; t[3] = v.w;
    }
    __syncthreads();
#pragma unroll
    for (int j = 0; j < 2; ++j) {
        int f = j * 256 + tid;
        int orow = f >> 3, kc = f & 7;
        unsigned short pk[8];
#pragma unroll
        for (int q = 0; q < 8; ++q) pk[q] = f2bf(tile[(kc * 8 + q) * 65 + orow]);
        *(uint4*)(dst + (size_t)(c0 + orow) * R + r0 + kc * 8) = *(uint4*)pk;
    }
}

// ---------------- router ----------------
__global__ void router_kernel(const float* __restrict__ x, const float* __restrict__ Wg,
                              const float* __restrict__ bg,
                              int* __restrict__ eidx, float* __restrict__ gate_p,
                              int* __restrict__ counts, float* __restrict__ ce_sum) {
    __shared__ float ceS[8];
    __shared__ int   cntS[8];
    int tid = threadIdx.x;
    if (tid < 8) { ceS[tid] = 0.f; cntS[tid] = 0; }
    __syncthreads();

    int wid = tid >> 6, lane = tid & 63;
    int t = blockIdx.x * 16 + wid;
    const float* xr = x + (size_t)t * D_MODEL;

    float acc[8];
#pragma unroll
    for (int e = 0; e < 8; ++e) acc[e] = 0.f;

#pragma unroll
    for (int c = 0; c < 4; ++c) {
        int i0 = c * 256 + lane * 4;
        float4 xv = *(const float4*)(xr + i0);
#pragma unroll
        for (int j = 0; j < 4; ++j) {
            const float* wr = Wg + (size_t)(i0 + j) * 8;
            float4 lo = *(const float4*)(wr);
            float4 hi = *(const float4*)(wr + 4);
            float xs = (&xv.x)[j];
            acc[0] += xs * lo.x; acc[1] += xs * lo.y;
            acc[2] += xs * lo.z; acc[3] += xs * lo.w;
            acc[4] += xs * hi.x; acc[5] += xs * hi.y;
            acc[6] += xs * hi.z; acc[7] += xs * hi.w;
        }
    }
#pragma unroll
    for (int e = 0; e < 8; ++e) {
#pragma unroll
        for (int off = 32; off > 0; off >>= 1)
            acc[e] += __shfl_xor(acc[e], off, 64);
    }

    if (lane == 0) {
        float lg[8];
#pragma unroll
        for (int e = 0; e < 8; ++e) lg[e] = acc[e] + bg[e];
        float mx = lg[0]; int am = 0;
#pragma unroll
        for (int e = 1; e < 8; ++e) { if (lg[e] > mx) { mx = lg[e]; am = e; } }
        float ex[8], s = 0.f;
#pragma unroll
        for (int e = 0; e < 8; ++e) { ex[e] = __expf(lg[e] - mx); s += ex[e]; }
        float inv = 1.f / s;
#pragma unroll
        for (int e = 0; e < 8; ++e) atomicAdd(&ceS[e], ex[e] * inv);
        atomicAdd(&cntS[am], 1);
        eidx[t] = am;
        gate_p[t] = ex[am] * inv;
    }
    __syncthreads();
    if (tid < 8) atomicAdd(&ce_sum[tid], ceS[tid]);
    if (tid >= 8 && tid < 16) atomicAdd(&counts[tid - 8], cntS[tid - 8]);
}

// ---------------- offsets + aux loss ----------------
__global__ void offsets_aux_kernel(const int* __restrict__ counts, const float* __restrict__ ce_sum,
                                   int* __restrict__ offs, float* __restrict__ aux_out) {
    if (threadIdx.x == 0) {
        int off = 0; float aux = 0.f;
        for (int e = 0; e < 8; ++e) {
            offs[e] = off; off += counts[e];
            aux += ((float)counts[e] / (float)NTOK) * (ce_sum[e] / (float)NTOK);
        }
        aux_out[0] = ALPHA * (float)NEXP * aux;
    }
}

// ---------------- scatter ----------------
__global__ void scatter_kernel(const int* __restrict__ eidx, const int* __restrict__ offs,
                               int* __restrict__ fill, int* __restrict__ toks) {
    int t = blockIdx.x * 256 + threadIdx.x;
    int e = eidx[t];
    int pos = atomicAdd(&fill[e], 1);
    toks[offs[e] + pos] = t;
}

// ======================= GEMM1 =======================
// h = silu(X WuT^T) * (X WvT^T). 128m x 64n tile, BK=64, 4 waves (64x32 each).
// Static ping-pong double-buffer (64KB LDS, 2 blocks/CU), 1 barrier per K-step.
// XCD-pinned 1D grid: id = e + 8*(mt + 32*nt) -> expert e lives on XCD e.

#define G1_STAGE(AS, BUS, BVS)                                            \
    {                                                                     \
        _Pragma("unroll")                                                 \
        for (int i = 0; i < 4; ++i) { gload_lds16(aS[i], &AS[aOff[i]]); aS[i] += 64; } \
        _Pragma("unroll")                                                 \
        for (int i = 0; i < 2; ++i) {                                     \
            gload_lds16(buS[i], &BUS[bOff[i]]); buS[i] += 64;             \
            gload_lds16(bvS[i], &BVS[bOff[i]]); bvS[i] += 64;             \
        }                                                                 \
    }

#define G1_COMPUTE(AS, BUS, BVS)                                          \
    {                                                                     \
        _Pragma("unroll")                                                 \
        for (int kk = 0; kk < 2; ++kk) {                                  \
            const int g = kk * 4 + lchunk;                                \
            bf16x8 af[4], bu[2], bv[2];                                   \
            _Pragma("unroll")                                             \
            for (int m = 0; m < 4; ++m) {                                 \
                int r = rbase + m * 16 + lrow;                            \
                af[m] = ldsFrag(&AS[r * 64 + ((g ^ (r & 7)) * 8)]);       \
            }                                                             \
            _Pragma("unroll")                                             \
            for (int n = 0; n < 2; ++n) {                                 \
                int rn = cbase + n * 16 + lrow;                           \
                int off = rn * 64 + ((g ^ (rn & 7)) * 8);                 \
                bu[n] = ldsFrag(&BUS[off]);                               \
                bv[n] = ldsFrag(&BVS[off]);                               \
            }                                                             \
            __builtin_amdgcn_s_setprio(1);                                \
            _Pragma("unroll")                                             \
            for (int m = 0; m < 4; ++m)                                   \
                _Pragma("unroll")                                         \
                for (int n = 0; n < 2; ++n) {                             \
                    accU[m][n] = __builtin_amdgcn_mfma_f32_16x16x32_bf16(af[m], bu[n], accU[m][n], 0, 0, 0); \
                    accV[m][n] = __builtin_amdgcn_mfma_f32_16x16x32_bf16(af[m], bv[n], accV[m][n], 0, 0, 0); \
                }                                                         \
            __builtin_amdgcn_s_setprio(0);                                \
        }                                                                 \
    }

__global__ __launch_bounds__(256, 2) void gemm1_kernel(
    const unsigned short* __restrict__ WuT, const unsigned short* __restrict__ WvT,
    const unsigned short* __restrict__ xbf,
    const int* __restrict__ toks, const int* __restrict__ counts, const int* __restrict__ offs,
    unsigned short* __restrict__ hbuf) {
    const int id = blockIdx.x;
    const int e  = id & 7;
    const int j  = id >> 3;
    const int mt = j & 31;
    const int nt = j >> 5;          // 0..42
    const int Ne = counts[e];
    if (mt * 128 >= Ne) return;
    const int slot0 = offs[e] + mt * 128;
    const int rowsV = min(128, Ne - mt * 128);
    const int ncol0 = nt * 64;

    __shared__ unsigned short As0[128 * 64];
    __shared__ unsigned short As1[128 * 64];
    __shared__ unsigned short Bus0[64 * 64];
    __shared__ unsigned short Bus1[64 * 64];
    __shared__ unsigned short Bvs0[64 * 64];
    __shared__ unsigned short Bvs1[64 * 64];

    const int tid = threadIdx.x;

    const unsigned short* aS[4];
    int aOff[4];
#pragma unroll
    for (int i = 0; i < 4; ++i) {
        int c = i * 256 + tid;
        int r = c >> 3, ch = c & 7;
        int srcOff = (ch ^ (r & 7)) * 8;
        int ar = min(r, rowsV - 1);
        int tok = toks[slot0 + ar];
        aS[i] = xbf + (size_t)tok * D_MODEL + srcOff;
        aOff[i] = c * 8;
    }
    const unsigned short *buS[2], *bvS[2];
    int bOff[2];
#pragma unroll
    for (int i = 0; i < 2; ++i) {
        int c = i * 256 + tid;
        int r = c >> 3, ch = c & 7;
        int srcOff = (ch ^ (r & 7)) * 8;
        int bn = ncol0 + r;
        buS[i] = WuT + ((size_t)e * HID + bn) * D_MODEL + srcOff;
        bvS[i] = WvT + ((size_t)e * HID + bn) * D_MODEL + srcOff;
        bOff[i] = c * 8;
    }

    f32x4 accU[4][2], accV[4][2];
#pragma unroll
    for (int m = 0; m < 4; ++m)
#pragma unroll
        for (int n = 0; n < 2; ++n) {
            accU[m][n] = (f32x4){0.f, 0.f, 0.f, 0.f};
            accV[m][n] = (f32x4){0.f, 0.f, 0.f, 0.f};
        }

    const int lane = tid & 63;
    const int w = tid >> 6;
    const int rbase = (w >> 1) * 64;
    const int cbase = (w & 1) * 32;
    const int lrow = lane & 15;
    const int lchunk = lane >> 4;

    // prologue: step 0 -> buf0
    G1_STAGE(As0, Bus0, Bvs0);
    __syncthreads();

    // 16 K-steps, 2 per iteration, static ping-pong
#pragma unroll 1
    for (int k2 = 0; k2 < 8; ++k2) {
        G1_STAGE(As1, Bus1, Bvs1);       // step 2k+1
        G1_COMPUTE(As0, Bus0, Bvs0);     // step 2k
        __syncthreads();
        if (k2 < 7) G1_STAGE(As0, Bus0, Bvs0);   // step 2k+2
        G1_COMPUTE(As1, Bus1, Bvs1);     // step 2k+1
        __syncthreads();
    }

    // epilogue: h = silu(u) * v (bf16)
#pragma unroll
    for (int m = 0; m < 4; ++m) {
#pragma unroll
        for (int i = 0; i < 4; ++i) {
            int r = rbase + m * 16 + (lane >> 4) * 4 + i;
            if (r >= rowsV) continue;
            size_t rowOff = (size_t)(slot0 + r) * HID + ncol0;
#pragma unroll
            for (int n = 0; n < 2; ++n) {
                int c = cbase + n * 16 + (lane & 15);
                float u = accU[m][n][i];
                float v = accV[m][n][i];
                float s = u / (1.f + __expf(-u));
                hbuf[rowOff + c] = f2bf(s * v);
            }
        }
    }
}

// ======================= GEMM2 =======================
// y[tok] = p * (h WdT^T). 128m x 64n, BK=64, static ping-pong dbuf (48KB LDS).
// XCD-pinned 1D grid: id = e + 8*(mt + 32*nt).

#define G2_STAGE(AS, BS)                                                  \
    {                                                                     \
        _Pragma("unroll")                                                 \
        for (int i = 0; i < 4; ++i) { gload_lds16(aS[i], &AS[aOff[i]]); aS[i] += 64; } \
        _Pragma("unroll")                                                 \
        for (int i = 0; i < 2; ++i) { gload_lds16(bS[i], &BS[bOff[i]]); bS[i] += 64; } \
    }

#define G2_COMPUTE(AS, BS)                                                \
    {                                                                     \
        _Pragma("unroll")                                                 \
        for (int kk = 0; kk < 2; ++kk) {                                  \
            const int g = kk * 4 + lchunk;                                \
            bf16x8 af[4], bf[2];                                          \
            _Pragma("unroll")                                             \
            for (int m = 0; m < 4; ++m) {                                 \
                int r = rbase + m * 16 + lrow;                            \
                af[m] = ldsFrag(&AS[r * 64 + ((g ^ (r & 7)) * 8)]);       \
            }                                                             \
            _Pragma("unroll")                                             \
            for (int n = 0; n < 2; ++n) {                                 \
                int rn = cbase + n * 16 + lrow;                           \
                bf[n] = ldsFrag(&BS[rn * 64 + ((g ^ (rn & 7)) * 8)]);     \
            }                                                             \
            __builtin_amdgcn_s_setprio(1);                                \
            _Pragma("unroll")                                             \
            for (int m = 0; m < 4; ++m)                                   \
                _Pragma("unroll")                                         \
                for (int n = 0; n < 2; ++n)                               \
                    acc[m][n] = __builtin_amdgcn_mfma_f32_16x16x32_bf16(af[m], bf[n], acc[m][n], 0, 0, 0); \
            __builtin_amdgcn_s_setprio(0);                                \
        }                                                                 \
    }

__global__ __launch_bounds__(256, 2) void gemm2_kernel(
    const unsigned short* __restrict__ WdT, const unsigned short* __restrict__ hbuf,
    const int* __restrict__ toks, const int* __restrict__ counts, const int* __restrict__ offs,
    const float* __restrict__ gate_p, float* __restrict__ yout) {
    const int id = blockIdx.x;
    const int e  = id & 7;
    const int j  = id >> 3;
    const int mt = j & 31;
    const int nt = j >> 5;          // 0..15
    const int Ne = counts[e];
    if (mt * 128 >= Ne) return;
    const int slot0 = offs[e] + mt * 128;
    const int rowsV = min(128, Ne - mt * 128);
    const int ncol0 = nt * 64;

    __shared__ unsigned short As0[128 * 64];
    __shared__ unsigned short As1[128 * 64];
    __shared__ unsigned short Bs0[64 * 64];
    __shared__ unsigned short Bs1[64 * 64];

    const int tid = threadIdx.x;

    const unsigned short* aS[4];
    int aOff[4];
#pragma unroll
    for (int i = 0; i < 4; ++i) {
        int c = i * 256 + tid;
        int r = c >> 3, ch = c & 7;
        int srcOff = (ch ^ (r & 7)) * 8;
        int ar = min(r, rowsV - 1);
        aS[i] = hbuf + (size_t)(slot0 + ar) * HID + srcOff;
        aOff[i] = c * 8;
    }
    const unsigned short* bS[2];
    int bOff[2];
#pragma unroll
    for (int i = 0; i < 2; ++i) {
        int c = i * 256 + tid;
        int r = c >> 3, ch = c & 7;
        int srcOff = (ch ^ (r & 7)) * 8;
        bS[i] = WdT + ((size_t)e * D_MODEL + ncol0 + r) * HID + srcOff;
        bOff[i] = c * 8;
    }

    f32x4 acc[4][2];
#pragma unroll
    for (int m = 0; m < 4; ++m)
#pragma unroll
        for (int n = 0; n < 2; ++n) acc[m][n] = (f32x4){0.f, 0.f, 0.f, 0.f};

    const int lane = tid & 63;
    const int w = tid >> 6;
    const int rbase = (w >> 1) * 64;
    const int cbase = (w & 1) * 32;
    const int lrow = lane & 15;
    const int lchunk = lane >> 4;

    // prologue: step 0 -> buf0
    G2_STAGE(As0, Bs0);
    __syncthreads();

    // 43 K-steps: 21 ping-pong pairs (steps 0..41) + epilogue step 42 in buf0
#pragma unroll 1
    for (int k2 = 0; k2 < 21; ++k2) {
        G2_STAGE(As1, Bs1);          // step 2k+1
        G2_COMPUTE(As0, Bs0);        // step 2k
        __syncthreads();
        G2_STAGE(As0, Bs0);          // step 2k+2  (<= 42)
        G2_COMPUTE(As1, Bs1);        // step 2k+1
        __syncthreads();
    }
    G2_COMPUTE(As0, Bs0);            // step 42

#pragma unroll
    for (int m = 0; m < 4; ++m) {
#pragma unroll
        for (int i = 0; i < 4; ++i) {
            int r = rbase + m * 16 + (lane >> 4) * 4 + i;
            if (r >= rowsV) continue;
            int tok = toks[slot0 + r];
            float p = gate_p[tok];
            float* yrow = yout + (size_t)tok * D_MODEL + ncol0;
#pragma unroll
            for (int n = 0; n < 2; ++n) {
                int c = cbase + n * 16 + (lane & 15);
                yrow[c] = p * acc[m][n][i];
            }
        }
    }
}

// ---------------- launch ----------------
extern "C" void kernel_launch(void* const* d_in, const int* in_sizes, int n_in,
                              void* d_out, int out_size, void* d_ws, size_t ws_size,
                              hipStream_t stream) {
    const float* x  = (const float*)d_in[0];
    const float* Wg = (const float*)d_in[1];
    const float* bg = (const float*)d_in[2];
    const float* Wu = (const float*)d_in[3];
    const float* Wv = (const float*)d_in[4];
    const float* Wd = (const float*)d_in[5];
    float* yout = (float*)d_out;
    float* aux_out = yout + (size_t)NTOK * D_MODEL;

    char* ws = (char*)d_ws;
    int*   counts = (int*)(ws + 0);
    int*   offs   = (int*)(ws + 32);
    float* ce_sum = (float*)(ws + 64);
    int*   fill   = (int*)(ws + 96);
    int*   eidx   = (int*)(ws + 128);
    float* gate_p = (float*)(ws + 16512);
    int*   toks   = (int*)(ws + 32896);
    unsigned short* xbf  = (unsigned short*)(ws + 65536);      // 8 MB
    unsigned short* hbuf = (unsigned short*)(ws + 8454144);    // 22.5 MB
    unsigned short* WuT  = (unsigned short*)(ws + 30998528);   // 45 MB
    unsigned short* WvT  = (unsigned short*)(ws + 76087296);   // 45 MB
    unsigned short* WdT  = WuT;                                // reused after gemm1

    hipMemsetAsync(ws, 0, 128, stream);
    tobf16_kernel<<<2048, 256, 0, stream>>>(x, xbf);
    router_kernel<<<256, 1024, 0, stream>>>(x, Wg, bg, eidx, gate_p, counts, ce_sum);
    offsets_aux_kernel<<<1, 64, 0, stream>>>(counts, ce_sum, offs, aux_out);
    scatter_kernel<<<16, 256, 0, stream>>>(eidx, offs, fill, toks);
    transposeUV_kernel<<<dim3(HID / 64, D_MODEL / 64, 16), 256, 0, stream>>>(Wu, Wv, WuT, WvT);
    gemm1_kernel<<<8 * 32 * 43, 256, 0, stream>>>(WuT, WvT, xbf, toks, counts, offs, hbuf);
    transpose_kernel<<<dim3(D_MODEL / 64, HID / 64, 8), 256, 0, stream>>>(Wd, WdT, HID, D_MODEL);
    gemm2_kernel<<<8 * 32 * 16, 256, 0, stream>>>(WdT, hbuf, toks, counts, offs, gate_p, yout);
}

// Round 7
// 266.050 us; speedup vs baseline: 3.3550x; 1.0111x over previous
//
#include <hip/hip_runtime.h>

// ---------------- problem constants ----------------
#define D_MODEL 1024
#define HID     2752
#define NEXP    8
#define NTOK    4096
#define ALPHA   0.05f

// gemm1 grid: e(8) x mt(32) x nt(22) ; transpose-role blocks appended after
#define G1_BLOCKS (8 * 32 * 22)
#define WDT_TILES (16 * 43 * 8)

typedef __bf16 bf16_t;
typedef bf16_t bf16x8 __attribute__((ext_vector_type(8)));
typedef float  f32x4  __attribute__((ext_vector_type(4)));

__device__ inline unsigned short f2bf(float f) {
    unsigned int u = __float_as_uint(f);
    u += 0x7fffu + ((u >> 16) & 1u);   // round-to-nearest-even
    return (unsigned short)(u >> 16);
}

__device__ inline bf16x8 ldsFrag(const unsigned short* p) {
    union { uint4 u; bf16x8 b; } t;
    t.u = *(const uint4*)p;
    return t.b;
}

__device__ inline void gload_lds16(const void* g, void* l) {
    __builtin_amdgcn_global_load_lds((const __attribute__((address_space(1))) void*)g,
                                     (__attribute__((address_space(3))) void*)l, 16, 0, 0);
}

// ---------------- weight transpose+convert: [R][C] f32 -> [C][R] bf16 ----------------
__global__ __launch_bounds__(256) void transposeUV_kernel(const float* __restrict__ Wu,
                                                          const float* __restrict__ Wv,
                                                          unsigned short* __restrict__ WuT,
                                                          unsigned short* __restrict__ WvT) {
    __shared__ float tile[64 * 65];
    const int z = blockIdx.z;
    const int e = z & 7;
    const float* src = ((z < 8) ? Wu : Wv) + (size_t)e * D_MODEL * HID;
    unsigned short* dst = ((z < 8) ? WuT : WvT) + (size_t)e * D_MODEL * HID;
    const int c0 = blockIdx.x * 64, r0 = blockIdx.y * 64;
    const int tid = threadIdx.x;
#pragma unroll
    for (int j = 0; j < 4; ++j) {
        int f = j * 256 + tid;
        int row = f >> 4, c4 = f & 15;
        float4 v = *(const float4*)(src + (size_t)(r0 + row) * HID + c0 + c4 * 4);
        float* t = &tile[row * 65 + c4 * 4];
        t[0] = v.x; t[1] = v.y; t[2] = v.z; t[3] = v.w;
    }
    __syncthreads();
#pragma unroll
    for (int j = 0; j < 2; ++j) {
        int f = j * 256 + tid;
        int orow = f >> 3, kc = f & 7;
        unsigned short pk[8];
#pragma unroll
        for (int q = 0; q < 8; ++q) pk[q] = f2bf(tile[(kc * 8 + q) * 65 + orow]);
        *(uint4*)(dst + (size_t)(c0 + orow) * D_MODEL + r0 + kc * 8) = *(uint4*)pk;
    }
}

// standalone Wd transpose (fallback when ws too small to fuse)
__global__ __launch_bounds__(256) void transpose_kernel(const float* __restrict__ in,
                                                        unsigned short* __restrict__ out,
                                                        int R, int C) {
    __shared__ float tile[64 * 65];
    const int e = blockIdx.z;
    const float* src = in + (size_t)e * R * C;
    unsigned short* dst = out + (size_t)e * R * C;
    const int c0 = blockIdx.x * 64, r0 = blockIdx.y * 64;
    const int tid = threadIdx.x;
#pragma unroll
    for (int j = 0; j < 4; ++j) {
        int f = j * 256 + tid;
        int row = f >> 4, c4 = f & 15;
        float4 v = *(const float4*)(src + (size_t)(r0 + row) * C + c0 + c4 * 4);
        float* t = &tile[row * 65 + c4 * 4];
        t[0] = v.x; t[1] = v.y; t[2] = v.z; t[3] = v.w;
    }
    __syncthreads();
#pragma unroll
    for (int j = 0; j < 2; ++j) {
        int f = j * 256 + tid;
        int orow = f >> 3, kc = f & 7;
        unsigned short pk[8];
#pragma unroll
        for (int q = 0; q < 8; ++q) pk[q] = f2bf(tile[(kc * 8 + q) * 65 + orow]);
        *(uint4*)(dst + (size_t)(c0 + orow) * R + r0 + kc * 8) = *(uint4*)pk;
    }
}

// ---------------- router (fused x->bf16 conversion) ----------------
__global__ void router_kernel(const float* __restrict__ x, const float* __restrict__ Wg,
                              const float* __restrict__ bg,
                              int* __restrict__ eidx, float* __restrict__ gate_p,
                              int* __restrict__ counts, float* __restrict__ ce_sum,
                              unsigned short* __restrict__ xbf) {
    __shared__ float ceS[8];
    __shared__ int   cntS[8];
    int tid = threadIdx.x;
    if (tid < 8) { ceS[tid] = 0.f; cntS[tid] = 0; }
    __syncthreads();

    int wid = tid >> 6, lane = tid & 63;
    int t = blockIdx.x * 16 + wid;
    const float* xr = x + (size_t)t * D_MODEL;
    unsigned short* xbr = xbf + (size_t)t * D_MODEL;

    float acc[8];
#pragma unroll
    for (int e = 0; e < 8; ++e) acc[e] = 0.f;

#pragma unroll
    for (int c = 0; c < 4; ++c) {
        int i0 = c * 256 + lane * 4;
        float4 xv = *(const float4*)(xr + i0);
        uint2 pk;
        pk.x = (unsigned)f2bf(xv.x) | ((unsigned)f2bf(xv.y) << 16);
        pk.y = (unsigned)f2bf(xv.z) | ((unsigned)f2bf(xv.w) << 16);
        *(uint2*)(xbr + i0) = pk;
#pragma unroll
        for (int j = 0; j < 4; ++j) {
            const float* wr = Wg + (size_t)(i0 + j) * 8;
            float4 lo = *(const float4*)(wr);
            float4 hi = *(const float4*)(wr + 4);
            float xs = (&xv.x)[j];
            acc[0] += xs * lo.x; acc[1] += xs * lo.y;
            acc[2] += xs * lo.z; acc[3] += xs * lo.w;
            acc[4] += xs * hi.x; acc[5] += xs * hi.y;
            acc[6] += xs * hi.z; acc[7] += xs * hi.w;
        }
    }
#pragma unroll
    for (int e = 0; e < 8; ++e) {
#pragma unroll
        for (int off = 32; off > 0; off >>= 1)
            acc[e] += __shfl_xor(acc[e], off, 64);
    }

    if (lane == 0) {
        float lg[8];
#pragma unroll
        for (int e = 0; e < 8; ++e) lg[e] = acc[e] + bg[e];
        float mx = lg[0]; int am = 0;
#pragma unroll
        for (int e = 1; e < 8; ++e) { if (lg[e] > mx) { mx = lg[e]; am = e; } }
        float ex[8], s = 0.f;
#pragma unroll
        for (int e = 0; e < 8; ++e) { ex[e] = __expf(lg[e] - mx); s += ex[e]; }
        float inv = 1.f / s;
#pragma unroll
        for (int e = 0; e < 8; ++e) atomicAdd(&ceS[e], ex[e] * inv);
        atomicAdd(&cntS[am], 1);
        eidx[t] = am;
        gate_p[t] = ex[am] * inv;
    }
    __syncthreads();
    if (tid < 8) atomicAdd(&ce_sum[tid], ceS[tid]);
    if (tid >= 8 && tid < 16) atomicAdd(&counts[tid - 8], cntS[tid - 8]);
}

// ---------------- offsets + aux loss ----------------
__global__ void offsets_aux_kernel(const int* __restrict__ counts, const float* __restrict__ ce_sum,
                                   int* __restrict__ offs, float* __restrict__ aux_out) {
    if (threadIdx.x == 0) {
        int off = 0; float aux = 0.f;
        for (int e = 0; e < 8; ++e) {
            offs[e] = off; off += counts[e];
            aux += ((float)counts[e] / (float)NTOK) * (ce_sum[e] / (float)NTOK);
        }
        aux_out[0] = ALPHA * (float)NEXP * aux;
    }
}

// ---------------- scatter ----------------
__global__ void scatter_kernel(const int* __restrict__ eidx, const int* __restrict__ offs,
                               int* __restrict__ fill, int* __restrict__ toks) {
    int t = blockIdx.x * 256 + threadIdx.x;
    int e = eidx[t];
    int pos = atomicAdd(&fill[e], 1);
    toks[offs[e] + pos] = t;
}

// ======================= GEMM1 (+ fused Wd transpose role) =======================
// gemm1 role: round-2 proven structure. 128x128 tile, BK=64, 4 waves, single-buffer,
// 2 barriers per K-step. XCD-pinned 1D grid: id = e + 8*(mt + 32*nt).
// transpose role (ids >= G1_BLOCKS, only when fused): Wd [2752][1024] f32 -> WdT bf16.
__global__ __launch_bounds__(256, 2) void gemm1_kernel(
    const unsigned short* __restrict__ WuT, const unsigned short* __restrict__ WvT,
    const unsigned short* __restrict__ xbf,
    const int* __restrict__ toks, const int* __restrict__ counts, const int* __restrict__ offs,
    unsigned short* __restrict__ hbuf,
    const float* __restrict__ Wd, unsigned short* __restrict__ WdT) {

    __shared__ __align__(16) unsigned char ldsbuf[48 * 1024];
    unsigned short* As  = (unsigned short*)ldsbuf;
    unsigned short* Bus = (unsigned short*)(ldsbuf + 16384);
    unsigned short* Bvs = (unsigned short*)(ldsbuf + 32768);

    const int id = blockIdx.x;
    const int tid = threadIdx.x;

    if (id >= G1_BLOCKS) {
        // ---- Wd transpose role ----
        const int t  = id - G1_BLOCKS;
        const int xt = t & 15;           // tile along C = D_MODEL
        const int rr = t >> 4;
        const int yt = rr % 43;          // tile along R = HID
        const int e2 = rr / 43;
        const float* src = Wd + (size_t)e2 * HID * D_MODEL;
        unsigned short* dst = WdT + (size_t)e2 * HID * D_MODEL;
        const int c0 = xt * 64, r0 = yt * 64;
        float* tile = (float*)ldsbuf;    // 64*65*4 = 16.6 KB < 48 KB
#pragma unroll
        for (int j = 0; j < 4; ++j) {
            int f = j * 256 + tid;
            int row = f >> 4, c4 = f & 15;
            float4 v = *(const float4*)(src + (size_t)(r0 + row) * D_MODEL + c0 + c4 * 4);
            float* tp = &tile[row * 65 + c4 * 4];
            tp[0] = v.x; tp[1] = v.y; tp[2] = v.z; tp[3] = v.w;
        }
        __syncthreads();
#pragma unroll
        for (int j = 0; j < 2; ++j) {
            int f = j * 256 + tid;
            int orow = f >> 3, kc = f & 7;
            unsigned short pk[8];
#pragma unroll
            for (int q = 0; q < 8; ++q) pk[q] = f2bf(tile[(kc * 8 + q) * 65 + orow]);
            *(uint4*)(dst + (size_t)(c0 + orow) * HID + r0 + kc * 8) = *(uint4*)pk;
        }
        return;
    }

    // ---- gemm1 role ----
    const int e  = id & 7;
    const int j  = id >> 3;
    const int mt = j & 31;
    const int nt = j >> 5;               // 0..21
    const int Ne = counts[e];
    if (mt * 128 >= Ne) return;
    const int slot0 = offs[e] + mt * 128;
    const int rowsV = min(128, Ne - mt * 128);
    const int ncol0 = nt * 128;
    const int colsV = min(128, HID - ncol0);

    const unsigned short* aS[4];
    const unsigned short* buS[4];
    const unsigned short* bvS[4];
    unsigned short* aD[4];
    unsigned short* buD[4];
    unsigned short* bvD[4];
#pragma unroll
    for (int i = 0; i < 4; ++i) {
        int c = i * 256 + tid;
        int r = c >> 3, ch = c & 7;
        int srcOff = ((ch ^ (r & 7)) * 8);
        int ar = min(r, rowsV - 1);
        int tok = toks[slot0 + ar];
        aS[i] = xbf + (size_t)tok * D_MODEL + srcOff;
        int bn = ncol0 + min(r, colsV - 1);
        buS[i] = WuT + ((size_t)e * HID + bn) * D_MODEL + srcOff;
        bvS[i] = WvT + ((size_t)e * HID + bn) * D_MODEL + srcOff;
        aD[i]  = As  + c * 8;
        buD[i] = Bus + c * 8;
        bvD[i] = Bvs + c * 8;
    }

    f32x4 accU[4][4], accV[4][4];
#pragma unroll
    for (int m = 0; m < 4; ++m)
#pragma unroll
        for (int n = 0; n < 4; ++n) {
            accU[m][n] = (f32x4){0.f, 0.f, 0.f, 0.f};
            accV[m][n] = (f32x4){0.f, 0.f, 0.f, 0.f};
        }

    const int lane = tid & 63;
    const int w = tid >> 6;
    const int rbase = (w >> 1) * 64;
    const int cbase = (w & 1) * 64;
    const int lrow = lane & 15;
    const int lchunk = lane >> 4;

    for (int ks = 0; ks < 16; ++ks) {
#pragma unroll
        for (int i = 0; i < 4; ++i) gload_lds16(aS[i],  aD[i]);
#pragma unroll
        for (int i = 0; i < 4; ++i) gload_lds16(buS[i], buD[i]);
#pragma unroll
        for (int i = 0; i < 4; ++i) gload_lds16(bvS[i], bvD[i]);
#pragma unroll
        for (int i = 0; i < 4; ++i) { aS[i] += 64; buS[i] += 64; bvS[i] += 64; }
        __syncthreads();

#pragma unroll
        for (int kk = 0; kk < 2; ++kk) {
            const int g = kk * 4 + lchunk;
            bf16x8 af[4], bu[4], bv[4];
#pragma unroll
            for (int m = 0; m < 4; ++m) {
                int r = rbase + m * 16 + lrow;
                af[m] = ldsFrag(&As[r * 64 + ((g ^ (r & 7)) * 8)]);
            }
#pragma unroll
            for (int n = 0; n < 4; ++n) {
                int rn = cbase + n * 16 + lrow;
                int off = rn * 64 + ((g ^ (rn & 7)) * 8);
                bu[n] = ldsFrag(&Bus[off]);
                bv[n] = ldsFrag(&Bvs[off]);
            }
#pragma unroll
            for (int m = 0; m < 4; ++m)
#pragma unroll
                for (int n = 0; n < 4; ++n) {
                    accU[m][n] = __builtin_amdgcn_mfma_f32_16x16x32_bf16(af[m], bu[n], accU[m][n], 0, 0, 0);
                    accV[m][n] = __builtin_amdgcn_mfma_f32_16x16x32_bf16(af[m], bv[n], accV[m][n], 0, 0, 0);
                }
        }
        __syncthreads();
    }

    // epilogue: h = silu(u) * v (bf16)
#pragma unroll
    for (int m = 0; m < 4; ++m) {
#pragma unroll
        for (int i = 0; i < 4; ++i) {
            int r = rbase + m * 16 + (lane >> 4) * 4 + i;
            if (r >= rowsV) continue;
            size_t rowOff = (size_t)(slot0 + r) * HID + ncol0;
#pragma unroll
            for (int n = 0; n < 4; ++n) {
                int c = cbase + n * 16 + (lane & 15);
                if (c < colsV) {
                    float u = accU[m][n][i];
                    float v = accV[m][n][i];
                    float s = u / (1.f + __expf(-u));
                    hbuf[rowOff + c] = f2bf(s * v);
                }
            }
        }
    }
}

// ======================= GEMM2 =======================
// y[tok] = p * (h WdT^T). 128m x 64n, BK=64, static ping-pong dbuf (48KB LDS).
// XCD-pinned 1D grid: id = e + 8*(mt + 32*nt).

#define G2_STAGE(AS, BS)                                                  \
    {                                                                     \
        _Pragma("unroll")                                                 \
        for (int i = 0; i < 4; ++i) { gload_lds16(aS[i], &AS[aOff[i]]); aS[i] += 64; } \
        _Pragma("unroll")                                                 \
        for (int i = 0; i < 2; ++i) { gload_lds16(bS[i], &BS[bOff[i]]); bS[i] += 64; } \
    }

#define G2_COMPUTE(AS, BS)                                                \
    {                                                                     \
        _Pragma("unroll")                                                 \
        for (int kk = 0; kk < 2; ++kk) {                                  \
            const int g = kk * 4 + lchunk;                                \
            bf16x8 af[4], bf[2];                                          \
            _Pragma("unroll")                                             \
            for (int m = 0; m < 4; ++m) {                                 \
                int r = rbase + m * 16 + lrow;                            \
                af[m] = ldsFrag(&AS[r * 64 + ((g ^ (r & 7)) * 8)]);       \
            }                                                             \
            _Pragma("unroll")                                             \
            for (int n = 0; n < 2; ++n) {                                 \
                int rn = cbase + n * 16 + lrow;                           \
                bf[n] = ldsFrag(&BS[rn * 64 + ((g ^ (rn & 7)) * 8)]);     \
            }                                                             \
            __builtin_amdgcn_s_setprio(1);                                \
            _Pragma("unroll")                                             \
            for (int m = 0; m < 4; ++m)                                   \
                _Pragma("unroll")                                         \
                for (int n = 0; n < 2; ++n)                               \
                    acc[m][n] = __builtin_amdgcn_mfma_f32_16x16x32_bf16(af[m], bf[n], acc[m][n], 0, 0, 0); \
            __builtin_amdgcn_s_setprio(0);                                \
        }                                                                 \
    }

__global__ __launch_bounds__(256, 2) void gemm2_kernel(
    const unsigned short* __restrict__ WdT, const unsigned short* __restrict__ hbuf,
    const int* __restrict__ toks, const int* __restrict__ counts, const int* __restrict__ offs,
    const float* __restrict__ gate_p, float* __restrict__ yout) {
    const int id = blockIdx.x;
    const int e  = id & 7;
    const int j  = id >> 3;
    const int mt = j & 31;
    const int nt = j >> 5;          // 0..15
    const int Ne = counts[e];
    if (mt * 128 >= Ne) return;
    const int slot0 = offs[e] + mt * 128;
    const int rowsV = min(128, Ne - mt * 128);
    const int ncol0 = nt * 64;

    __shared__ unsigned short As0[128 * 64];
    __shared__ unsigned short As1[128 * 64];
    __shared__ unsigned short Bs0[64 * 64];
    __shared__ unsigned short Bs1[64 * 64];

    const int tid = threadIdx.x;

    const unsigned short* aS[4];
    int aOff[4];
#pragma unroll
    for (int i = 0; i < 4; ++i) {
        int c = i * 256 + tid;
        int r = c >> 3, ch = c & 7;
        int srcOff = (ch ^ (r & 7)) * 8;
        int ar = min(r, rowsV - 1);
        aS[i] = hbuf + (size_t)(slot0 + ar) * HID + srcOff;
        aOff[i] = c * 8;
    }
    const unsigned short* bS[2];
    int bOff[2];
#pragma unroll
    for (int i = 0; i < 2; ++i) {
        int c = i * 256 + tid;
        int r = c >> 3, ch = c & 7;
        int srcOff = (ch ^ (r & 7)) * 8;
        bS[i] = WdT + ((size_t)e * D_MODEL + ncol0 + r) * HID + srcOff;
        bOff[i] = c * 8;
    }

    f32x4 acc[4][2];
#pragma unroll
    for (int m = 0; m < 4; ++m)
#pragma unroll
        for (int n = 0; n < 2; ++n) acc[m][n] = (f32x4){0.f, 0.f, 0.f, 0.f};

    const int lane = tid & 63;
    const int w = tid >> 6;
    const int rbase = (w >> 1) * 64;
    const int cbase = (w & 1) * 32;
    const int lrow = lane & 15;
    const int lchunk = lane >> 4;

    // prologue: step 0 -> buf0
    G2_STAGE(As0, Bs0);
    __syncthreads();

    // 43 K-steps: 21 ping-pong pairs (steps 0..41) + epilogue step 42 in buf0
#pragma unroll 1
    for (int k2 = 0; k2 < 21; ++k2) {
        G2_STAGE(As1, Bs1);          // step 2k+1
        G2_COMPUTE(As0, Bs0);        // step 2k
        __syncthreads();
        G2_STAGE(As0, Bs0);          // step 2k+2  (<= 42)
        G2_COMPUTE(As1, Bs1);        // step 2k+1
        __syncthreads();
    }
    G2_COMPUTE(As0, Bs0);            // step 42

#pragma unroll
    for (int m = 0; m < 4; ++m) {
#pragma unroll
        for (int i = 0; i < 4; ++i) {
            int r = rbase + m * 16 + (lane >> 4) * 4 + i;
            if (r >= rowsV) continue;
            int tok = toks[slot0 + r];
            float p = gate_p[tok];
            float* yrow = yout + (size_t)tok * D_MODEL + ncol0;
#pragma unroll
            for (int n = 0; n < 2; ++n) {
                int c = cbase + n * 16 + (lane & 15);
                yrow[c] = p * acc[m][n][i];
            }
        }
    }
}

// ---------------- launch ----------------
extern "C" void kernel_launch(void* const* d_in, const int* in_sizes, int n_in,
                              void* d_out, int out_size, void* d_ws, size_t ws_size,
                              hipStream_t stream) {
    const float* x  = (const float*)d_in[0];
    const float* Wg = (const float*)d_in[1];
    const float* bg = (const float*)d_in[2];
    const float* Wu = (const float*)d_in[3];
    const float* Wv = (const float*)d_in[4];
    const float* Wd = (const float*)d_in[5];
    float* yout = (float*)d_out;
    float* aux_out = yout + (size_t)NTOK * D_MODEL;

    char* ws = (char*)d_ws;
    int*   counts = (int*)(ws + 0);
    int*   offs   = (int*)(ws + 32);
    float* ce_sum = (float*)(ws + 64);
    int*   fill   = (int*)(ws + 96);
    int*   eidx   = (int*)(ws + 128);
    float* gate_p = (float*)(ws + 16512);
    int*   toks   = (int*)(ws + 32896);
    unsigned short* xbf  = (unsigned short*)(ws + 65536);      // 8 MB
    unsigned short* hbuf = (unsigned short*)(ws + 8454144);    // 22.5 MB
    unsigned short* WuT  = (unsigned short*)(ws + 30998528);   // 43 MB
    unsigned short* WvT  = (unsigned short*)(ws + 76087296);   // 43 MB
    // separate WdT (43 MB) only if scratch allows; else reuse WuT after gemm1
    const size_t WDT_OFF = 121176064;
    const size_t WDT_SZ  = (size_t)NEXP * D_MODEL * HID * 2;
    const bool fused = ws_size >= WDT_OFF + WDT_SZ;
    unsigned short* WdT = fused ? (unsigned short*)(ws + WDT_OFF) : WuT;

    hipMemsetAsync(ws, 0, 128, stream);
    router_kernel<<<256, 1024, 0, stream>>>(x, Wg, bg, eidx, gate_p, counts, ce_sum, xbf);
    offsets_aux_kernel<<<1, 64, 0, stream>>>(counts, ce_sum, offs, aux_out);
    scatter_kernel<<<16, 256, 0, stream>>>(eidx, offs, fill, toks);
    transposeUV_kernel<<<dim3(HID / 64, D_MODEL / 64, 16), 256, 0, stream>>>(Wu, Wv, WuT, WvT);
    gemm1_kernel<<<fused ? (G1_BLOCKS + WDT_TILES) : G1_BLOCKS, 256, 0, stream>>>(
        WuT, WvT, xbf, toks, counts, offs, hbuf, Wd, WdT);
    if (!fused)
        transpose_kernel<<<dim3(D_MODEL / 64, HID / 64, 8), 256, 0, stream>>>(Wd, WdT, HID, D_MODEL);
    gemm2_kernel<<<8 * 32 * 16, 256, 0, stream>>>(WdT, hbuf, toks, counts, offs, gate_p, yout);
}